// Round 1
// baseline (43532.782 us; speedup 1.0000x reference)
//
#include <hip/hip_runtime.h>
#include <math.h>

#define D 256
#define SEQ 1000
#define NB 32
#define PATCH 160
#define NL 6
#define M_TOTAL (NB * SEQ)   // 32000
#define G3 (3 * D)           // 768

__device__ __forceinline__ float gelu_exact(float v) {
    return 0.5f * v * (1.0f + erff(v * 0.70710678118654752440f));
}

// ---------------------------------------------------------------------------
// Kernel 1: conv patchify GEMM + exact GELU + pos_emb add
// x[m][n] = gelu(sum_p wav[b, s*160+p] * cw[p][n]) + pos[s][n],  m = b*SEQ+s
// Tiled 64x64, K-chunks of 32. Grid (500, 4), 256 threads.
// ---------------------------------------------------------------------------
__global__ __launch_bounds__(256) void conv_gelu_pos(
    const float* __restrict__ wav, const float* __restrict__ cw,
    const float* __restrict__ pos, float* __restrict__ x)
{
    __shared__ float As[64][33];
    __shared__ float Bs[32][65];
    const int m0 = blockIdx.x * 64;
    const int n0 = blockIdx.y * 64;
    const int tid = threadIdx.x;
    const int tx = tid & 15;      // 0..15 -> n
    const int ty = tid >> 4;      // 0..15 -> m
    float acc[4][4] = {};

    for (int kc = 0; kc < PATCH; kc += 32) {
        // A tile: 64 rows x 32 k
        for (int p = 0; p < 8; ++p) {
            int mr = p * 8 + (tid >> 5);
            int kk = tid & 31;
            int m = m0 + mr;
            int b = m / SEQ, s = m % SEQ;
            As[mr][kk] = wav[(size_t)b * 160000 + (size_t)s * PATCH + kc + kk];
        }
        // B tile: 32 k x 64 n
        for (int p = 0; p < 8; ++p) {
            int kr = p * 4 + (tid >> 6);
            int nn = tid & 63;
            Bs[kr][nn] = cw[(size_t)(kc + kr) * D + n0 + nn];
        }
        __syncthreads();
        #pragma unroll
        for (int kk = 0; kk < 32; ++kk) {
            float a[4], bb[4];
            #pragma unroll
            for (int i = 0; i < 4; ++i) a[i] = As[ty * 4 + i][kk];
            #pragma unroll
            for (int j = 0; j < 4; ++j) bb[j] = Bs[kk][tx * 4 + j];
            #pragma unroll
            for (int i = 0; i < 4; ++i)
                #pragma unroll
                for (int j = 0; j < 4; ++j)
                    acc[i][j] = fmaf(a[i], bb[j], acc[i][j]);
        }
        __syncthreads();
    }
    // epilogue: gelu + pos, float4 stores
    #pragma unroll
    for (int i = 0; i < 4; ++i) {
        int m = m0 + ty * 4 + i;
        int s = m % SEQ;
        int n = n0 + tx * 4;
        float4 v;
        v.x = gelu_exact(acc[i][0]) + pos[(size_t)s * D + n + 0];
        v.y = gelu_exact(acc[i][1]) + pos[(size_t)s * D + n + 1];
        v.z = gelu_exact(acc[i][2]) + pos[(size_t)s * D + n + 2];
        v.w = gelu_exact(acc[i][3]) + pos[(size_t)s * D + n + 3];
        *(float4*)&x[(size_t)m * D + n] = v;
    }
}

// ---------------------------------------------------------------------------
// Kernel 2: per-row mean / rstd (LayerNorm stats). One wave per row.
// ---------------------------------------------------------------------------
__global__ __launch_bounds__(64) void row_stats(
    const float* __restrict__ x, float* __restrict__ st)
{
    const int m = blockIdx.x;
    const int t = threadIdx.x;
    const float* r = x + (size_t)m * D;
    float s = 0.f, q = 0.f;
    #pragma unroll
    for (int i = 0; i < 4; ++i) {
        float v = r[t + 64 * i];
        s += v;
        q += v * v;
    }
    #pragma unroll
    for (int o = 32; o > 0; o >>= 1) {
        s += __shfl_down(s, o);
        q += __shfl_down(q, o);
    }
    if (t == 0) {
        float mu = s * (1.f / 256.f);
        float var = q * (1.f / 256.f) - mu * mu;
        st[2 * m]     = mu;
        st[2 * m + 1] = rsqrtf(var + 1e-5f);
    }
}

// ---------------------------------------------------------------------------
// Kernel 3: fused LN + input-projection GEMM
// xp[m][g] = sum_k ((x[m][k]-mu)*rstd*lnsc[k]+lnbi[k]) * w_ih[g][k] + b_ih[g]
// Tiled 64x64, K=256 in chunks of 32. Grid (500, 12), 256 threads.
// ---------------------------------------------------------------------------
__global__ __launch_bounds__(256) void ln_xp_gemm(
    const float* __restrict__ x, const float* __restrict__ st,
    const float* __restrict__ lnsc, const float* __restrict__ lnbi,
    const float* __restrict__ wih, const float* __restrict__ bih,
    float* __restrict__ xp)
{
    __shared__ float As[64][33];
    __shared__ float Bs[32][65];
    __shared__ float sc[D], bi[D];
    const int m0 = blockIdx.x * 64;
    const int n0 = blockIdx.y * 64;
    const int tid = threadIdx.x;
    const int tx = tid & 15;
    const int ty = tid >> 4;
    sc[tid] = lnsc[tid];
    bi[tid] = lnbi[tid];
    float acc[4][4] = {};

    for (int kc = 0; kc < D; kc += 32) {
        for (int p = 0; p < 8; ++p) {
            int mr = p * 8 + (tid >> 5);
            int kk = tid & 31;
            int m = m0 + mr;
            float mu = st[2 * m], rs = st[2 * m + 1];
            float v = x[(size_t)m * D + kc + kk];
            As[mr][kk] = (v - mu) * rs * sc[kc + kk] + bi[kc + kk];
        }
        for (int p = 0; p < 8; ++p) {
            int nr = p * 8 + (tid >> 5);
            int kk = tid & 31;
            Bs[kk][nr] = wih[(size_t)(n0 + nr) * D + kc + kk];
        }
        __syncthreads();
        #pragma unroll
        for (int kk = 0; kk < 32; ++kk) {
            float a[4], bb[4];
            #pragma unroll
            for (int i = 0; i < 4; ++i) a[i] = As[ty * 4 + i][kk];
            #pragma unroll
            for (int j = 0; j < 4; ++j) bb[j] = Bs[kk][tx * 4 + j];
            #pragma unroll
            for (int i = 0; i < 4; ++i)
                #pragma unroll
                for (int j = 0; j < 4; ++j)
                    acc[i][j] = fmaf(a[i], bb[j], acc[i][j]);
        }
        __syncthreads();
    }
    #pragma unroll
    for (int i = 0; i < 4; ++i) {
        int m = m0 + ty * 4 + i;
        int n = n0 + tx * 4;
        float4 v;
        v.x = acc[i][0] + bih[n + 0];
        v.y = acc[i][1] + bih[n + 1];
        v.z = acc[i][2] + bih[n + 2];
        v.w = acc[i][3] + bih[n + 3];
        *(float4*)&xp[(size_t)m * G3 + n] = v;
    }
}

// ---------------------------------------------------------------------------
// Kernel 4: transpose w_hh [768][256] -> whT [256][768] for coalesced scan
// ---------------------------------------------------------------------------
__global__ __launch_bounds__(256) void transpose_whh(
    const float* __restrict__ whh, float* __restrict__ whT)
{
    __shared__ float t[32][33];
    const int g0 = blockIdx.x * 32;
    const int k0 = blockIdx.y * 32;
    const int lx = threadIdx.x & 31;
    const int ly = threadIdx.x >> 5;   // 0..7
    for (int i = 0; i < 32; i += 8)
        t[ly + i][lx] = whh[(size_t)(g0 + ly + i) * D + k0 + lx];
    __syncthreads();
    for (int i = 0; i < 32; i += 8)
        whT[(size_t)(k0 + ly + i) * G3 + g0 + lx] = t[lx][ly + i];
}

// ---------------------------------------------------------------------------
// Kernel 5: GRU recurrence. One block per batch, 512 threads (K split 2-way).
// h kept in LDS (double-buffered), w_hh streamed from L2 (whT layout).
// Residual x += h written in-place.
// ---------------------------------------------------------------------------
__global__ __launch_bounds__(512) void gru_scan(
    const float* __restrict__ xp, const float* __restrict__ whT,
    const float* __restrict__ bhh, float* __restrict__ x)
{
    __shared__ float hs[2][D];
    __shared__ float pr[3][D];
    const int tid = threadIdx.x;
    const int d = tid & 255;
    const int half = tid >> 8;        // 0 or 1
    const int b = blockIdx.x;
    if (tid < D) hs[0][tid] = 0.f;
    const float bh_r = bhh[d];
    const float bh_z = bhh[D + d];
    const float bh_n = bhh[2 * D + d];
    const float* xpb = xp + (size_t)b * SEQ * G3;
    float* xb = x + (size_t)b * SEQ * D;
    __syncthreads();
    int p = 0;
    for (int t = 0; t < SEQ; ++t) {
        const float* h = hs[p];
        const int k0 = half << 7;
        const float* wbase = whT + (size_t)k0 * G3;
        float ar = 0.f, az = 0.f, an = 0.f;
        #pragma unroll 8
        for (int k = 0; k < 128; ++k) {
            float hv = h[k0 + k];
            const float* w = wbase + (size_t)k * G3;
            ar = fmaf(hv, w[d], ar);
            az = fmaf(hv, w[D + d], az);
            an = fmaf(hv, w[2 * D + d], an);
        }
        float xr = 0.f, xz = 0.f, xn = 0.f, xold = 0.f;
        if (half) {
            pr[0][d] = ar; pr[1][d] = az; pr[2][d] = an;
        } else {
            const float* xpt = xpb + (size_t)t * G3;
            xr = xpt[d]; xz = xpt[D + d]; xn = xpt[2 * D + d];
            xold = xb[(size_t)t * D + d];
        }
        __syncthreads();
        if (!half) {
            float gr = xr + ar + pr[0][d] + bh_r;
            float gz = xz + az + pr[1][d] + bh_z;
            float gn =      an + pr[2][d] + bh_n;
            float r = 1.f / (1.f + expf(-gr));
            float z = 1.f / (1.f + expf(-gz));
            float n = tanhf(xn + r * gn);
            float hnew = (1.f - z) * n + z * h[d];
            xb[(size_t)t * D + d] = xold + hnew;
            hs[1 - p][d] = hnew;
        }
        __syncthreads();
        p ^= 1;
    }
}

// ---------------------------------------------------------------------------
// Kernel 6: final LN + mean-pool over sequence
// emb[b][d] = fsc[d] * mean_s((x[b,s,d]-mu)*rstd) + fbi[d]
// ---------------------------------------------------------------------------
__global__ __launch_bounds__(256) void pool_ln(
    const float* __restrict__ x, const float* __restrict__ st,
    const float* __restrict__ fsc, const float* __restrict__ fbi,
    float* __restrict__ emb)
{
    const int b = blockIdx.x;
    const int d = threadIdx.x;
    float acc = 0.f;
    for (int s = 0; s < SEQ; ++s) {
        int m = b * SEQ + s;
        acc += (x[(size_t)m * D + d] - st[2 * m]) * st[2 * m + 1];
    }
    emb[b * D + d] = (acc * (1.f / (float)SEQ)) * fsc[d] + fbi[d];
}

// ---------------------------------------------------------------------------
// Kernel 7: classification head (tiny). Single block.
// ---------------------------------------------------------------------------
__global__ __launch_bounds__(256) void head_mlp(
    const float* __restrict__ emb, const float* __restrict__ w1,
    const float* __restrict__ b1, const float* __restrict__ w2,
    const float* __restrict__ b2, float* __restrict__ out)
{
    __shared__ float es[NB][D + 1];
    __shared__ float h1[NB][128 + 1];
    const int t = threadIdx.x;
    for (int i = t; i < NB * D; i += 256) es[i / D][i % D] = emb[i];
    __syncthreads();
    for (int i = t; i < NB * 128; i += 256) {
        int bb = i / 128, j = i % 128;
        float a = b1[j];
        for (int k = 0; k < D; ++k) a = fmaf(es[bb][k], w1[(size_t)k * 128 + j], a);
        h1[bb][j] = gelu_exact(a);
    }
    __syncthreads();
    for (int i = t; i < NB * 8; i += 256) {
        int bb = i / 8, c = i % 8;
        float a = b2[c];
        for (int k = 0; k < 128; ++k) a = fmaf(h1[bb][k], w2[(size_t)k * 8 + c], a);
        out[i] = a;
    }
}

// ---------------------------------------------------------------------------
extern "C" void kernel_launch(void* const* d_in, const int* in_sizes, int n_in,
                              void* d_out, int out_size, void* d_ws, size_t ws_size,
                              hipStream_t stream)
{
    const float* wav  = (const float*)d_in[0];
    const float* cw   = (const float*)d_in[1];
    const float* pos  = (const float*)d_in[2];
    const float* lnsc = (const float*)d_in[3];
    const float* lnbi = (const float*)d_in[4];
    const float* wih  = (const float*)d_in[5];
    const float* whh  = (const float*)d_in[6];
    const float* bih  = (const float*)d_in[7];
    const float* bhh  = (const float*)d_in[8];
    const float* fsc  = (const float*)d_in[9];
    const float* fbi  = (const float*)d_in[10];
    const float* hw1  = (const float*)d_in[11];
    const float* hb1  = (const float*)d_in[12];
    const float* hw2  = (const float*)d_in[13];
    const float* hb2  = (const float*)d_in[14];

    float* ws    = (float*)d_ws;
    float* x     = ws;                       // 8,192,000 f
    float* xp    = x + (size_t)M_TOTAL * D;  // 24,576,000 f
    float* st    = xp + (size_t)M_TOTAL * G3;// 64,000 f
    float* whT   = st + 2 * M_TOTAL;         // 196,608 f
    float* emb   = whT + D * G3;             // 8,192 f

    conv_gelu_pos<<<dim3(M_TOTAL / 64, D / 64), 256, 0, stream>>>(wav, cw, pos, x);

    for (int l = 0; l < NL; ++l) {
        row_stats<<<M_TOTAL, 64, 0, stream>>>(x, st);
        ln_xp_gemm<<<dim3(M_TOTAL / 64, G3 / 64), 256, 0, stream>>>(
            x, st, lnsc + (size_t)l * D, lnbi + (size_t)l * D,
            wih + (size_t)l * G3 * D, bih + (size_t)l * G3, xp);
        transpose_whh<<<dim3(G3 / 32, D / 32), 256, 0, stream>>>(
            whh + (size_t)l * G3 * D, whT);
        gru_scan<<<NB, 512, 0, stream>>>(xp, whT, bhh + (size_t)l * G3, x);
    }

    row_stats<<<M_TOTAL, 64, 0, stream>>>(x, st);
    pool_ln<<<NB, D, 0, stream>>>(x, st, fsc, fbi, emb);
    head_mlp<<<1, 256, 0, stream>>>(emb, hw1, hb1, hw2, hb2, (float*)d_out);
}